// Round 11
// baseline (32.638 us; speedup 1.0000x reference)
//
#include <hip/hip_runtime.h>

// HilbertFlatten: out[s] = x[hilbert_decode(s)] for (256,256,256) f32.
// Persistent pipelined waves: each wave owns 4 consecutive 8^3 regions
// (2048 curve pts). Double-buffered LDS region staging via global_load_lds
// (16B/lane), counted vmcnt waits (never full drain mid-pipe): decode and
// NT stores of region r overlap the in-flight loads of region r+1.
// Whole grid resident (8192 waves = 32/CU) -> one generation.

typedef float f32x4 __attribute__((ext_vector_type(4)));
typedef __attribute__((address_space(1))) const void global_cvoid;
typedef __attribute__((address_space(3))) void lds_void;
typedef __attribute__((address_space(3))) float lds_float;

__device__ __forceinline__ void decode8(unsigned S, unsigned B[3],
                                        unsigned& baseflat) {
    unsigned g = S ^ (S >> 1);
    unsigned G[3];
#pragma unroll
    for (int d = 0; d < 3; ++d) {
        unsigned v = (g >> (2 - d)) & 0x00249249u;
        v = (v ^ (v >> 2)) & 0x030C30C3u;
        v = (v ^ (v >> 4)) & 0x0300F00Fu;
        v = (v ^ (v >> 8)) & 0x000000FFu;
        G[d] = v;
    }
    G[0] |= 0x100u; G[1] |= 0x200u; G[2] |= 0x400u;
#pragma unroll
    for (int bit = 6; bit >= 0; --bit) {
        const unsigned low = ((1u << (7 - bit)) - 1u) | 0x0F00u;
#pragma unroll
        for (int dim = 2; dim >= 0; --dim) {
            unsigned m = (G[dim] >> (7 - bit)) & 1u;
            unsigned diff = (G[0] ^ G[dim]) & low;
            unsigned t = diff & (m - 1u);
            G[0] ^= ((0u - m) & low) ^ t;
            G[dim] ^= t;
        }
    }
    unsigned s3m = 0u - ((S >> 3) & 1u);
    unsigned V0 = (0xF0u ^ s3m) & 0xFFu;
    const unsigned V1 = 0x3Cu, V2 = 0x66u;
#pragma unroll
    for (int d = 0; d < 3; ++d) {
        unsigned cd = 0u - ((G[d] >> 11) & 1u);
        unsigned a0 = (0u - ((G[d] >> 8) & 1u)) ^ cd;
        unsigned a1 = (0u - ((G[d] >> 9) & 1u)) ^ cd;
        unsigned a2 = (0u - ((G[d] >> 10) & 1u)) ^ cd;
        B[d] = ((a0 & V0) ^ (a1 & V1) ^ (a2 & V2) ^ cd) & 0xFFu;
    }
    baseflat = ((G[0] & 0xFEu) << 16) | ((G[1] & 0xFEu) << 8) | (G[2] & 0xFEu);
}

__device__ __forceinline__ void issue_loads(const float* __restrict__ x,
                                            unsigned rf, lds_float* dst,
                                            unsigned lane) {
    unsigned dxl = lane >> 4;
    unsigned dyl = (lane >> 1) & 7u;
    unsigned half = lane & 1u;
    const float* gb = x + rf;
#pragma unroll
    for (unsigned h = 0; h < 2; ++h) {
        const float* src = gb + (h * 4u + dxl) * 65536u + dyl * 256u + half * 4u;
        __builtin_amdgcn_global_load_lds((global_cvoid*)src,
                                         (lds_void*)(dst + h * 256u), 16, 0, 0);
    }
}

__device__ __forceinline__ void process_store(const float* lw,
                                              const unsigned B[3],
                                              unsigned baseflat,
                                              float* __restrict__ outp,
                                              unsigned lane) {
    unsigned bx = (baseflat >> 16) & 6u;
    unsigned by = (baseflat >> 8) & 6u;
    unsigned bz = baseflat & 6u;
    unsigned bxp = (bx >> 1) & 1u;
    unsigned byp = (by >> 1) & 1u;
    float2 r0 = *(const float2*)&lw[(bx + byp) * 64u + (by + bxp) * 8u + bz];
    float2 r1 = *(const float2*)&lw[(bx + byp) * 64u + (by + (bxp ^ 1u)) * 8u + bz];
    float2 r2 = *(const float2*)&lw[(bx + (byp ^ 1u)) * 64u + (by + bxp) * 8u + bz];
    float2 r3 = *(const float2*)&lw[(bx + (byp ^ 1u)) * 64u + (by + (bxp ^ 1u)) * 8u + bz];
    bool sx = bxp != 0u, sy = byp != 0u;
    float2 a0 = sx ? r1 : r0;
    float2 a1 = sx ? r0 : r1;
    float2 a2 = sx ? r3 : r2;
    float2 a3 = sx ? r2 : r3;
    float2 q00 = sy ? a2 : a0;
    float2 q01 = sy ? a3 : a1;
    float2 q10 = sy ? a0 : a2;
    float2 q11 = sy ? a1 : a3;

    float o8[8];
#pragma unroll
    for (int rr = 0; rr < 8; ++rr) {
        unsigned f0 = (B[0] >> rr) & 1u;
        unsigned f1 = (B[1] >> rr) & 1u;
        unsigned f2 = (B[2] >> rr) & 1u;
        float2 t0 = f1 ? q01 : q00;
        float2 t1 = f1 ? q11 : q10;
        float2 t  = f0 ? t1 : t0;
        o8[rr] = f2 ? t.y : t.x;
    }

    int src1 = (int)(lane >> 1);
    int src2 = (int)(32u + (lane >> 1));
    bool hi = (lane & 1u) != 0u;
    float vA[4], vB[4];
#pragma unroll
    for (int j = 0; j < 4; ++j) {
        float a = __shfl(o8[j], src1, 64);
        float bb = __shfl(o8[4 + j], src1, 64);
        vA[j] = hi ? bb : a;
        float c = __shfl(o8[j], src2, 64);
        float d = __shfl(o8[4 + j], src2, 64);
        vB[j] = hi ? d : c;
    }
    __builtin_nontemporal_store((f32x4){vA[0], vA[1], vA[2], vA[3]},
                                (f32x4*)(outp + 4u * lane));
    __builtin_nontemporal_store((f32x4){vB[0], vB[1], vB[2], vB[3]},
                                (f32x4*)(outp + 256u + 4u * lane));
}

__global__ __launch_bounds__(256) void hilbert_pipe_kernel(
    const float* __restrict__ x, float* __restrict__ out) {
    __shared__ float lds[4 * 1024];          // per wave: 2 bufs x 512 floats
    // XCD-chunked bijective swizzle (gridDim.x = 2048, divisible by 8).
    unsigned nb = blockIdx.x;
    unsigned cpx = gridDim.x >> 3;
    unsigned b = (nb & 7u) * cpx + (nb >> 3);
    unsigned tid = threadIdx.x;
    unsigned lane = tid & 63u;
    unsigned wave = tid >> 6;
    unsigned W = b * 4u + wave;              // global wave id
    unsigned Sw = W * 2048u;                 // wave's first curve point

    const float* lw = lds + wave * 1024u;
    lds_float* lw3 = (lds_float*)lds + wave * 1024u;

    unsigned B0[3], B1[3], B2[3], B3[3], bf0, bf1, bf2, bf3;

    // Prologue: fill the 2-deep pipe.
    decode8(Sw + lane * 8u, B0, bf0);
    issue_loads(x, bf0 & 0x00F8F8F8u, lw3, lane);            // +2
    decode8(Sw + 512u + lane * 8u, B1, bf1);
    issue_loads(x, bf1 & 0x00F8F8F8u, lw3 + 512u, lane);     // +2

    // r=0: outstanding = loads0(2)+loads1(2); need loads0 -> vmcnt(2)
    asm volatile("s_waitcnt vmcnt(2)" ::: "memory");
    process_store(lw, B0, bf0, out + Sw, lane);              // +2 NT stores
    decode8(Sw + 1024u + lane * 8u, B2, bf2);
    issue_loads(x, bf2 & 0x00F8F8F8u, lw3, lane);            // +2 (buf0)

    // r=1: after loads1: stores0(2)+loads2(2) -> vmcnt(4)
    asm volatile("s_waitcnt vmcnt(4)" ::: "memory");
    process_store(lw + 512u, B1, bf1, out + Sw + 512u, lane);
    decode8(Sw + 1536u + lane * 8u, B3, bf3);
    issue_loads(x, bf3 & 0x00F8F8F8u, lw3 + 512u, lane);     // +2 (buf1)

    // r=2: after loads2: stores1(2)+loads3(2) -> vmcnt(4)
    asm volatile("s_waitcnt vmcnt(4)" ::: "memory");
    process_store(lw, B2, bf2, out + Sw + 1024u, lane);

    // r=3: after loads3: stores2(2) -> vmcnt(2)
    asm volatile("s_waitcnt vmcnt(2)" ::: "memory");
    process_store(lw + 512u, B3, bf3, out + Sw + 1536u, lane);
}

extern "C" void kernel_launch(void* const* d_in, const int* in_sizes, int n_in,
                              void* d_out, int out_size, void* d_ws, size_t ws_size,
                              hipStream_t stream) {
    const float* x = (const float*)d_in[0];
    float* out = (float*)d_out;
    unsigned n = (unsigned)out_size;            // 16777216
    unsigned nwaves = n / 2048u;                // 8192 (2048 pts per wave)
    unsigned blocks = nwaves / 4u;              // 2048 (divisible by 8)
    hilbert_pipe_kernel<<<blocks, 256, 0, stream>>>(x, out);
}

// Round 12
// 27.397 us; speedup vs baseline: 1.1913x; 1.1913x over previous
//
#include <hip/hip_runtime.h>

// HilbertFlatten: out[s] = x[hilbert_decode(s)] for (256,256,256) f32.
// Block = one 16^3 region = 4096 consecutive curve points (Hilbert property:
// 4096-aligned block occupies an aligned 16-cube). Stage region into 16KB LDS
// with 16x global_load_lds of FULL 64B lines (zero read waste, fully
// sequential); chunk-XOR swizzle via pre-swizzled global source (rule:
// both-sides-or-neither). After one barrier, each wave does two passes; per
// pass lanes gather their 2x2x2 cube from LDS (corner-rotation + swizzle ->
// ~2-way banks) and emit shuffle-paired fully-contiguous 1KB NT stores (R7).

typedef float f32x4 __attribute__((ext_vector_type(4)));
typedef __attribute__((address_space(1))) const void global_cvoid;
typedef __attribute__((address_space(3))) void lds_void;
typedef __attribute__((address_space(3))) float lds_float;

__device__ __forceinline__ void decode8(unsigned S, unsigned B[3],
                                        unsigned& baseflat) {
    unsigned g = S ^ (S >> 1);
    unsigned G[3];
#pragma unroll
    for (int d = 0; d < 3; ++d) {
        unsigned v = (g >> (2 - d)) & 0x00249249u;
        v = (v ^ (v >> 2)) & 0x030C30C3u;
        v = (v ^ (v >> 4)) & 0x0300F00Fu;
        v = (v ^ (v >> 8)) & 0x000000FFu;
        G[d] = v;
    }
    G[0] |= 0x100u; G[1] |= 0x200u; G[2] |= 0x400u;
#pragma unroll
    for (int bit = 6; bit >= 0; --bit) {
        const unsigned low = ((1u << (7 - bit)) - 1u) | 0x0F00u;
#pragma unroll
        for (int dim = 2; dim >= 0; --dim) {
            unsigned m = (G[dim] >> (7 - bit)) & 1u;
            unsigned diff = (G[0] ^ G[dim]) & low;
            unsigned t = diff & (m - 1u);
            G[0] ^= ((0u - m) & low) ^ t;
            G[dim] ^= t;
        }
    }
    unsigned s3m = 0u - ((S >> 3) & 1u);
    unsigned V0 = (0xF0u ^ s3m) & 0xFFu;
    const unsigned V1 = 0x3Cu, V2 = 0x66u;
#pragma unroll
    for (int d = 0; d < 3; ++d) {
        unsigned cd = 0u - ((G[d] >> 11) & 1u);
        unsigned a0 = (0u - ((G[d] >> 8) & 1u)) ^ cd;
        unsigned a1 = (0u - ((G[d] >> 9) & 1u)) ^ cd;
        unsigned a2 = (0u - ((G[d] >> 10) & 1u)) ^ cd;
        B[d] = ((a0 & V0) ^ (a1 & V1) ^ (a2 & V2) ^ cd) & 0xFFu;
    }
    baseflat = ((G[0] & 0xFEu) << 16) | ((G[1] & 0xFEu) << 8) | (G[2] & 0xFEu);
}

// Read float2 at LOCAL region coords (ix,iy,iz even) from swizzled LDS.
__device__ __forceinline__ float2 lds_read2(const float* lds, unsigned ix,
                                            unsigned iy, unsigned iz) {
    unsigned c = ix * 64u + iy * 4u + (iz >> 2);
    unsigned k = ((ix >> 1) & 3u) ^ ((iy >> 1) & 3u);
    unsigned w = ((c ^ k) << 2) | (iz & 3u);
    return *(const float2*)&lds[w];
}

__global__ __launch_bounds__(256) void hilbert_blk_kernel(
    const float* __restrict__ x, float* __restrict__ out) {
    __shared__ float lds[4096];              // 16 KB: one 16^3 region
    // XCD-chunked bijective swizzle (gridDim.x = 4096, divisible by 8).
    unsigned nb = blockIdx.x;
    unsigned cpx = gridDim.x >> 3;
    unsigned b = (nb & 7u) * cpx + (nb >> 3);
    unsigned tid = threadIdx.x;
    unsigned lane = tid & 63u;
    unsigned wave = tid >> 6;
    unsigned Sreg = b << 12;                 // region base curve index

    // Pass cubes: pass q covers curve [Sreg + 1024*wave + 512*q, +512),
    // lane owns 8 pts. Decode pass-0 cube first (corner needed for staging).
    unsigned B0[3], B1[3], bf0, bf1;
    decode8(Sreg + wave * 1024u + lane * 8u, B0, bf0);

    // ---- stage 16^3 region: full-line, sequential, pre-swizzled source ----
    unsigned X0 = (bf0 >> 16) & 0xF0u;
    unsigned Y0 = (bf0 >> 8) & 0xF0u;
    unsigned Z0 = bf0 & 0xF0u;
    const float* gb = x + (X0 * 65536u + Y0 * 256u + Z0);
    lds_float* lp = (lds_float*)lds;
    unsigned j = lane >> 2;                  // local y row 0..15
    unsigned qn = lane & 3u;                 // dest 16B quarter
#pragma unroll
    for (unsigned h = 0; h < 4; ++h) {
        unsigned i = wave * 4u + h;          // local x slice
        unsigned k = ((i >> 1) & 3u) ^ ((j >> 1) & 3u);
        unsigned qs = qn ^ k;                // source quarter (involution)
        const float* src = gb + i * 65536u + j * 256u + qs * 4u;
        __builtin_amdgcn_global_load_lds((global_cvoid*)src,
                                         (lds_void*)(lp + i * 256u + lane * 4u),
                                         16, 0, 0);
    }
    decode8(Sreg + wave * 1024u + 512u + lane * 8u, B1, bf1);  // overlap loads
    asm volatile("s_waitcnt vmcnt(0)" ::: "memory");
    __syncthreads();

    // ---- two passes: gather 2x2x2 cube from LDS, curve-order, NT store ----
#pragma unroll
    for (unsigned q = 0; q < 2; ++q) {
        unsigned bf = q ? bf1 : bf0;
        const unsigned* B = q ? B1 : B0;
        unsigned lx = (bf >> 16) & 14u;      // local, even
        unsigned ly = (bf >> 8) & 14u;
        unsigned lz = bf & 14u;
        unsigned bxp = (lx >> 1) & 1u;
        unsigned byp = (ly >> 1) & 1u;
        // corner-rotation read order (spreads bank parity per instruction)
        float2 r0 = lds_read2(lds, lx + byp,        ly + bxp,        lz);
        float2 r1 = lds_read2(lds, lx + byp,        ly + (bxp ^ 1u), lz);
        float2 r2 = lds_read2(lds, lx + (byp ^ 1u), ly + bxp,        lz);
        float2 r3 = lds_read2(lds, lx + (byp ^ 1u), ly + (bxp ^ 1u), lz);
        bool sx = bxp != 0u, sy = byp != 0u;
        float2 a0 = sx ? r1 : r0;
        float2 a1 = sx ? r0 : r1;
        float2 a2 = sx ? r3 : r2;
        float2 a3 = sx ? r2 : r3;
        float2 q00 = sy ? a2 : a0;
        float2 q01 = sy ? a3 : a1;
        float2 q10 = sy ? a0 : a2;
        float2 q11 = sy ? a1 : a3;

        float o8[8];
#pragma unroll
        for (int rr = 0; rr < 8; ++rr) {
            unsigned f0 = (B[0] >> rr) & 1u;
            unsigned f1 = (B[1] >> rr) & 1u;
            unsigned f2 = (B[2] >> rr) & 1u;
            float2 t0 = f1 ? q01 : q00;
            float2 t1 = f1 ? q11 : q10;
            float2 t  = f0 ? t1 : t0;
            o8[rr] = f2 ? t.y : t.x;
        }

        // Shuffle-paired fully-contiguous NT stores (2 x 1KB per pass).
        int src1 = (int)(lane >> 1);
        int src2 = (int)(32u + (lane >> 1));
        bool hi = (lane & 1u) != 0u;
        float vA[4], vB[4];
#pragma unroll
        for (int jj = 0; jj < 4; ++jj) {
            float a = __shfl(o8[jj], src1, 64);
            float bb = __shfl(o8[4 + jj], src1, 64);
            vA[jj] = hi ? bb : a;
            float c = __shfl(o8[jj], src2, 64);
            float d = __shfl(o8[4 + jj], src2, 64);
            vB[jj] = hi ? d : c;
        }
        unsigned WB = Sreg + wave * 1024u + q * 512u;
        __builtin_nontemporal_store((f32x4){vA[0], vA[1], vA[2], vA[3]},
                                    (f32x4*)(out + WB + 4u * lane));
        __builtin_nontemporal_store((f32x4){vB[0], vB[1], vB[2], vB[3]},
                                    (f32x4*)(out + WB + 256u + 4u * lane));
    }
}

extern "C" void kernel_launch(void* const* d_in, const int* in_sizes, int n_in,
                              void* d_out, int out_size, void* d_ws, size_t ws_size,
                              hipStream_t stream) {
    const float* x = (const float*)d_in[0];
    float* out = (float*)d_out;
    unsigned n = (unsigned)out_size;            // 16777216
    unsigned blocks = n >> 12;                  // 4096 regions (divisible by 8)
    hilbert_blk_kernel<<<blocks, 256, 0, stream>>>(x, out);
}

// Round 13
// 25.544 us; speedup vs baseline: 1.2777x; 1.0725x over previous
//
#include <hip/hip_runtime.h>

// HilbertFlatten: out[s] = x[hilbert_decode(s)] for (256,256,256) f32.
// FINAL (best-measured, R7 structure, 25.5us): 8 pts/thread probe-decode,
// 4x float2 cube loads (z-pairs contiguous), cndmask curve-order tree,
// shuffle-paired fully-contiguous 1KB nontemporal stores (full-line safe).
//
// Roofline evidence: six structural variants (per-lane gather, wave-region
// LDS, 4x-MLP, software-pipelined persistent waves, block 16^3 full-line
// staging, this) all land 25.5-27.4us with compulsory-minimal traffic
// (FETCH ~33MB L3-warm, WRITE ~65.5MB). ~130MB fabric movement / 25.5us
// = 5.1 TB/s aggregate = ~80% of this box's 6.4 TB/s streaming ceiling.

typedef float f32x4 __attribute__((ext_vector_type(4)));

__global__ __launch_bounds__(256) void hilbert_g8s_kernel(
    const float* __restrict__ x, float* __restrict__ out, unsigned ngroups) {
    // XCD-chunked bijective swizzle (gridDim.x divisible by 8).
    unsigned nb = blockIdx.x;
    unsigned cpx = gridDim.x >> 3;
    unsigned b = (nb & 7u) * cpx + (nb >> 3);
    unsigned tid = threadIdx.x;
    unsigned gid = b * 256u + tid;
    if (gid >= ngroups) return;          // never taken (exact grid)
    unsigned S = gid << 3;
    unsigned lane = tid & 63u;

    unsigned g = S ^ (S >> 1);
    unsigned G[3];
#pragma unroll
    for (int d = 0; d < 3; ++d) {
        unsigned v = (g >> (2 - d)) & 0x00249249u;
        v = (v ^ (v >> 2)) & 0x030C30C3u;
        v = (v ^ (v >> 4)) & 0x0300F00Fu;
        v = (v ^ (v >> 8)) & 0x000000FFu;
        G[d] = v;
    }
    // Probe channels: bits 8..10 identity basis, bit 11 affine constant.
    G[0] |= 0x100u; G[1] |= 0x200u; G[2] |= 0x400u;

#pragma unroll
    for (int bit = 6; bit >= 0; --bit) {
        const unsigned low = ((1u << (7 - bit)) - 1u) | 0x0F00u;
#pragma unroll
        for (int dim = 2; dim >= 0; --dim) {
            unsigned m = (G[dim] >> (7 - bit)) & 1u;
            unsigned diff = (G[0] ^ G[dim]) & low;
            unsigned t = diff & (m - 1u);
            G[0] ^= ((0u - m) & low) ^ t;
            G[dim] ^= t;
        }
    }

    // Per-offset init bit0 patterns over r=0..7.
    unsigned s3m = 0u - ((S >> 3) & 1u);
    unsigned V0 = (0xF0u ^ s3m) & 0xFFu;
    const unsigned V1 = 0x3Cu, V2 = 0x66u;

    unsigned B[3];
#pragma unroll
    for (int d = 0; d < 3; ++d) {
        unsigned cd = 0u - ((G[d] >> 11) & 1u);
        unsigned a0 = (0u - ((G[d] >> 8) & 1u)) ^ cd;
        unsigned a1 = (0u - ((G[d] >> 9) & 1u)) ^ cd;
        unsigned a2 = (0u - ((G[d] >> 10) & 1u)) ^ cd;
        B[d] = ((a0 & V0) ^ (a1 & V1) ^ (a2 & V2) ^ cd) & 0xFFu;
    }

    unsigned baseflat = ((G[0] & 0xFEu) << 16) | ((G[1] & 0xFEu) << 8)
                      | (G[2] & 0xFEu);

    // Load own 2x2x2 cube as 4 z-pair float2s.
    const float2* xp = (const float2*)(x + baseflat);
    float2 p00 = xp[0];
    float2 p01 = xp[128];
    float2 p10 = xp[32768];
    float2 p11 = xp[32768 + 128];

    float o8[8];
#pragma unroll
    for (int r = 0; r < 8; ++r) {
        unsigned f0 = (B[0] >> r) & 1u;
        unsigned f1 = (B[1] >> r) & 1u;
        unsigned f2 = (B[2] >> r) & 1u;
        float2 t0 = f1 ? p01 : p00;
        float2 t1 = f1 ? p11 : p10;
        float2 t  = f0 ? t1 : t0;
        o8[r] = f2 ? t.y : t.x;
    }

    // Shuffle-paired fully-contiguous stores.
    // Store A: floats [WB + 4*lane, +4) = thread (lane>>1)'s o8[(lane&1)*4..].
    // Store B: floats [WB + 256 + 4*lane, +4) = thread 32+(lane>>1)'s half.
    int src1 = (int)(lane >> 1);
    int src2 = (int)(32u + (lane >> 1));
    bool hi = (lane & 1u) != 0u;
    float vA[4], vB[4];
#pragma unroll
    for (int j = 0; j < 4; ++j) {
        float a = __shfl(o8[j], src1, 64);
        float bb = __shfl(o8[4 + j], src1, 64);
        vA[j] = hi ? bb : a;
        float c = __shfl(o8[j], src2, 64);
        float d = __shfl(o8[4 + j], src2, 64);
        vB[j] = hi ? d : c;
    }
    unsigned WB = (gid & ~63u) << 3;     // wave's first curve point
    f32x4* oA = (f32x4*)(out + WB + 4u * lane);
    f32x4* oB = (f32x4*)(out + WB + 256u + 4u * lane);
    __builtin_nontemporal_store((f32x4){vA[0], vA[1], vA[2], vA[3]}, oA);
    __builtin_nontemporal_store((f32x4){vB[0], vB[1], vB[2], vB[3]}, oB);
}

extern "C" void kernel_launch(void* const* d_in, const int* in_sizes, int n_in,
                              void* d_out, int out_size, void* d_ws, size_t ws_size,
                              hipStream_t stream) {
    const float* x = (const float*)d_in[0];
    float* out = (float*)d_out;
    unsigned n = (unsigned)out_size;               // 16777216
    unsigned ngroups = n >> 3;                     // 2097152
    unsigned blocks = (ngroups + 255u) / 256u;     // 8192 (divisible by 8)
    hilbert_g8s_kernel<<<blocks, 256, 0, stream>>>(x, out, ngroups);
}